// Round 3
// baseline (39.005 us; speedup 1.0000x reference)
//
#include <hip/hip_runtime.h>

#define NF 39
#define NP 741   // 39*38/2
#define N4 624   // float4s per row = 39*64/4

struct PairLUT { unsigned short rc[NP]; };

constexpr PairLUT make_lut() {
    PairLUT L{};
    int p = 0;
    for (int i = 0; i < NF; ++i)
        for (int j = i + 1; j < NF; ++j) {
            L.rc[p] = (unsigned short)((i << 8) | j);
            ++p;
        }
    return L;
}

__constant__ PairLUT LUT = make_lut();

__device__ __forceinline__ void load_row(const float4* __restrict__ xb4, int l,
                                         float4 (&t)[10]) {
    #pragma unroll
    for (int r = 0; r < 9; ++r) t[r] = xb4[r * 64 + l];
    t[9] = make_float4(0.f, 0.f, 0.f, 0.f);
    if (l < 48) t[9] = xb4[576 + l];
}

__device__ __forceinline__ void process_row(const float4 (&t)[10], int l,
                                            float* __restrict__ srow,
                                            float* __restrict__ ob) {
    // float4 index i4 = r*64+l belongs to field f = r*4 + l/16.
    #pragma unroll
    for (int r = 0; r < 10; ++r) {
        float vv = (t[r].x + t[r].y) + (t[r].z + t[r].w);
        vv += __shfl_xor(vv, 1);
        vv += __shfl_xor(vv, 2);
        vv += __shfl_xor(vv, 4);
        vv += __shfl_xor(vv, 8);
        const int f = r * 4 + (l >> 4);
        if ((l & 15) == 0 && f < NF) srow[f] = vv;
    }
    // Intra-wave LDS RAW/WAR: same-wave program order + compiler lgkmcnt waits.
    #pragma unroll
    for (int k = 0; k < 12; ++k) {
        const int p = k * 64 + l;
        if (p < NP) {
            const unsigned int rc = LUT.rc[p];
            __builtin_nontemporal_store(srow[rc >> 8] * srow[rc & 255u], ob + p);
        }
    }
}

__global__ __launch_bounds__(256) void opn_kernel(const float* __restrict__ x,
                                                  float* __restrict__ out) {
    const int tid = threadIdx.x;
    const int wid = tid >> 6;
    const int l   = tid & 63;
    const int gw  = blockIdx.x * 4 + wid;   // global wave id, 0..4095
    const size_t b0 = (size_t)gw * 4;       // 4 consecutive rows per wave

    __shared__ float s[4][NF + 1];
    float* srow = s[wid];

    const float4* x4 = reinterpret_cast<const float4*>(x);

    // 2-deep software pipeline: next row's 10 loads in flight while the
    // current row reduces + stores -> the read stream never drains.
    float4 ta[10], tb[10];
    load_row(x4 + b0 * N4,       l, ta);
    load_row(x4 + (b0 + 1) * N4, l, tb);

    process_row(ta, l, srow, out + b0 * NP);
    load_row(x4 + (b0 + 2) * N4, l, ta);

    process_row(tb, l, srow, out + (b0 + 1) * NP);
    load_row(x4 + (b0 + 3) * N4, l, tb);

    process_row(ta, l, srow, out + (b0 + 2) * NP);
    process_row(tb, l, srow, out + (b0 + 3) * NP);
}

extern "C" void kernel_launch(void* const* d_in, const int* in_sizes, int n_in,
                              void* d_out, int out_size, void* d_ws, size_t ws_size,
                              hipStream_t stream) {
    const float* x = (const float*)d_in[0];
    float* out = (float*)d_out;
    const int B = in_sizes[0] / (NF * 64);   // 16384
    // 4 rows/wave * 4 waves/block = 16 rows/block -> 1024 blocks
    opn_kernel<<<B / 16, 256, 0, stream>>>(x, out);
}

// Round 4
// 37.332 us; speedup vs baseline: 1.0448x; 1.0448x over previous
//
#include <hip/hip_runtime.h>

#define NF 39
#define NP 741   // 39*38/2
#define N4 624   // float4s per row = 39*64/4

struct PairLUT { unsigned short rc[NP]; };

constexpr PairLUT make_lut() {
    PairLUT L{};
    int p = 0;
    for (int i = 0; i < NF; ++i)
        for (int j = i + 1; j < NF; ++j) {
            L.rc[p] = (unsigned short)((i << 8) | j);
            ++p;
        }
    return L;
}

__constant__ PairLUT LUT = make_lut();

__global__ __launch_bounds__(256) void opn_kernel(const float* __restrict__ x,
                                                  float* __restrict__ out) {
    const int tid = threadIdx.x;
    const int wid = tid >> 6;   // wave id within block, 0..3
    const int l   = tid & 63;   // lane
    const int b   = blockIdx.x * 4 + wid;   // one row per wave

    __shared__ float s[4][NF + 1];

    const float4* xb4 = reinterpret_cast<const float4*>(x) + (size_t)b * N4;

    // 10 independent float4 loads per lane -> high MLP, all in flight at once.
    float v[10];
    #pragma unroll
    for (int r = 0; r < 9; ++r) {
        const float4 t = xb4[r * 64 + l];
        v[r] = (t.x + t.y) + (t.z + t.w);
    }
    {
        float4 t = {0.f, 0.f, 0.f, 0.f};
        if (576 + l < N4) t = xb4[576 + l];     // tail: 48 of 64 lanes
        v[9] = (t.x + t.y) + (t.z + t.w);
    }

    // float4 index i4 = r*64+l belongs to field f = i4/16 = r*4 + l/16.
    // Reduce each 16-lane group (same field) via shfl_xor; one lane stores to LDS.
    #pragma unroll
    for (int r = 0; r < 10; ++r) {
        float vv = v[r];
        vv += __shfl_xor(vv, 1);
        vv += __shfl_xor(vv, 2);
        vv += __shfl_xor(vv, 4);
        vv += __shfl_xor(vv, 8);
        const int f = r * 4 + (l >> 4);
        if ((l & 15) == 0 && f < NF) s[wid][f] = vv;
    }
    // Intra-wave LDS RAW: no __syncthreads needed (same wave, compiler emits
    // the lgkmcnt wait). Waves proceed independently -> no barrier coupling.

    float* ob = out + (size_t)b * NP;
    #pragma unroll
    for (int k = 0; k < 12; ++k) {
        const int p = k * 64 + l;
        if (p < NP) {
            const unsigned int rc = LUT.rc[p];
            // Nontemporal: don't let the 48.6 MB write stream evict the input
            // from L2/L3 (input+output ~= 212 MB < 256 MB Infinity Cache).
            __builtin_nontemporal_store(s[wid][rc >> 8] * s[wid][rc & 255u], ob + p);
        }
    }
}

extern "C" void kernel_launch(void* const* d_in, const int* in_sizes, int n_in,
                              void* d_out, int out_size, void* d_ws, size_t ws_size,
                              hipStream_t stream) {
    const float* x = (const float*)d_in[0];
    float* out = (float*)d_out;
    const int B = in_sizes[0] / (NF * 64);   // 16384
    opn_kernel<<<B / 4, 256, 0, stream>>>(x, out);
}